// Round 12
// baseline (283.781 us; speedup 1.0000x reference)
//
#include <hip/hip_runtime.h>
#include <hip/hip_bf16.h>

typedef __hip_bfloat16 bf16;
typedef unsigned int uint;
typedef unsigned short ushort;

using frag8 = __attribute__((ext_vector_type(8))) short;   // 8 bf16
using f32x4 = __attribute__((ext_vector_type(4))) float;

#define HWH 784     // 28*28
#define PPITCH 30   // padded plane pitch (shorts)
#define PPLANE 900  // 30*30 shorts per plane
#define PBLK 10800  // 12*900 shorts per (b,g)

// ---------------------------------------------------------------------------
// prep: merged fold_w2 + wprep + xpose + xwinsum. 1-D grid, block ranges:
//   [0, 12800)      xpose   (25 n-tiles x 8 c-tiles x 64 b)
//   [12800, 13568)  wprep   (768 rows)
//   [13568, 13676)  fold_w2 (108 blocks x 256)
//   [13676, 17772)  xwinsum (64 b x 64 cg): S'[b][w][c] = interior 12x12
//                   window MEAN of x (pre-scaled 1/144). Attention identity:
//                   window-mean(v) = W3*window-mean(x) + b3 (linear map
//                   commutes with uniform mean; interior windows lie fully
//                   inside the image) -> attmean kernel eliminated.
// ---------------------------------------------------------------------------
__global__ __launch_bounds__(256) void prep(const float* __restrict__ x,
                                            const float* __restrict__ w1,
                                            const float* __restrict__ w2,
                                            const float* __restrict__ w3,
                                            const float* __restrict__ b1,
                                            const float* __restrict__ b2,
                                            const float* __restrict__ b3,
                                            const float* __restrict__ fc_w,
                                            const float* __restrict__ dep_w,
                                            bf16* __restrict__ xT,
                                            bf16* __restrict__ wbf,
                                            float* __restrict__ W2,
                                            float* __restrict__ biascat,
                                            float* __restrict__ sbar) {
    __shared__ float t[32][33];
    const int bid = blockIdx.x, tid = threadIdx.x;

    if (bid < 12800) {
        // ---- xpose: x [b][c][n] f32 -> xT [b][n][c] bf16 (32x32 LDS tiles)
        const int n0 = (bid % 25) * 32;
        const int c0 = ((bid / 25) % 8) * 32;
        const int b  = bid / 200;
        const float* xb = x + (size_t)b * (256 * HWH);
#pragma unroll
        for (int e = tid; e < 1024; e += 256) {
            int r = e >> 5, col = e & 31;       // r: c-index, col: n-index
            int n = n0 + col;
            t[r][col] = (n < HWH) ? xb[(size_t)(c0 + r) * HWH + n] : 0.f;
        }
        __syncthreads();
#pragma unroll
        for (int e = tid; e < 512; e += 256) {
            int r = e >> 4, cp = (e & 15) * 2;  // r: n-index, cp: c-pair
            int n = n0 + r;
            if (n < HWH) {
                __hip_bfloat162 h;
                h.x = __float2bfloat16(t[cp][r]);
                h.y = __float2bfloat16(t[cp + 1][r]);
                *reinterpret_cast<__hip_bfloat162*>(
                    &xT[((size_t)b * HWH + n) * 256 + c0 + cp]) = h;
            }
        }
        return;
    }

    if (bid < 13568) {
        // ---- wprep: weights f32 -> bf16, concatenated [768][256]
        const int row = bid - 12800;
        const float* src = row < 256 ? w1 : (row < 512 ? w2 : w3);
        wbf[row * 256 + tid] = __float2bfloat16(src[(row & 255) * 256 + tid]);
        return;
    }

    if (bid < 13676) {
        // ---- fold_w2: W2[oc][c12][k9] = sum_o fc_w[o][c12]*dep_w[oc][o][k9]
        int idx = (bid - 13568) * 256 + tid;
        if (idx < 768) {
            const float* bs = idx < 256 ? b1 : (idx < 512 ? b2 : b3);
            biascat[idx] = bs[idx & 255];
        }
        if (idx >= 256 * 108) return;
        int oc  = idx / 108;
        int r   = idx % 108;
        int c12 = r / 9;
        int k9  = r % 9;
        float s = 0.f;
#pragma unroll
        for (int o = 0; o < 9; ++o)
            s += fc_w[o * 12 + c12] * dep_w[oc * 81 + o * 9 + k9];
        W2[idx] = s;
        return;
    }

    // ---- xwinsum: wave per channel; lanes 0..27 own columns (attmean shape)
    {
        const int q  = bid - 13676;
        const int b  = q >> 6, cg = q & 63;
        const int wave = tid >> 6, lane = tid & 63;
        const int c  = cg * 4 + wave;                     // channel 0..255
        const float* xp = x + ((size_t)b * 256 + c) * HWH;

        float cs[5] = {0.f, 0.f, 0.f, 0.f, 0.f};          // per-wi column sums
        if (lane < 28) {
#pragma unroll
            for (int y = 0; y < 28; ++y) {
                float v = xp[y * 28 + lane];
#pragma unroll
                for (int wi = 0; wi < 5; ++wi)
                    if (y >= 4 * wi && y <= 4 * wi + 11) cs[wi] += v;
            }
        }
#pragma unroll
        for (int wi = 0; wi < 5; ++wi) {
            float p = cs[wi];
#pragma unroll
            for (int d = 1; d < 32; d <<= 1) {            // inclusive prefix
                float t2 = __shfl_up(p, d);
                if (lane >= d) p += t2;
            }
            float hi = __shfl(p, 4 * lane + 11);          // valid for lane<5
            float lo = __shfl(p, 4 * lane - 1);
            if (lane < 5) {
                float w = hi - (lane ? lo : 0.f);
                // S'[b][w][c], w-major rows of 256 floats (coalesced in fused5)
                sbar[((size_t)b * 25 + wi * 5 + lane) * 256 + c] =
                    w * (1.0f / 144.0f);
            }
        }
    }
}

// ---------------------------------------------------------------------------
// MFMA GEMM (R6 verbatim, the benched best: 68 us):
// 128x128 tile, 2x2 wave grid, 16 KB LDS, 2 barriers/K-step, flat grid 2688
// with XCD-aware decode (FETCH 79->14 MB).
// K-loop surgery scoreboard (all on this structure, all LOST):
//   B-once 6mt/block 86us (R4) | B-once+prefetch 83us (R5) | dbuf 73us (R8:
//   __syncthreads == s_waitcnt vmcnt(0)+s_barrier drains same-step prefetch)
//   | BK=64 84us (R9: LDS 32KB halves residency) | wave-private+vmcnt(0)
//   110us (R10: full latency on each wave's own serial path) | operand-swap
//   68us but pitch-34 slowed downstream (R7).
// Verdict: structural at HIP source on this problem size. DO NOT revisit
// without an algorithmic change.
// perm output: PADDED pitch-30 planes, image (y,x) at (y+1)*30+x+1; borders
// garbage, consumers zero halo in LDS.
// m -> sec=m/256, ch=m%256, g=ch%64, head=ch/64, t=sec*4+head.
// ---------------------------------------------------------------------------
__device__ inline void load_lds16(const bf16* g, short* lds) {
    __builtin_amdgcn_global_load_lds(
        (const __attribute__((address_space(1))) void*)g,
        (__attribute__((address_space(3))) void*)lds, 16, 0, 0);
}

__global__ __launch_bounds__(256) void gemm_mfma(const bf16* __restrict__ wbf,
                                                 const float* __restrict__ biascat,
                                                 const bf16* __restrict__ xT,
                                                 bf16* __restrict__ perm) {
    __shared__ short lds[8192];                 // A: [0,4096) shorts, B: [4096,8192)

    const int tid  = threadIdx.x;
    const int wave = tid >> 6, lane = tid & 63;

    // XCD-aware decode: X=s&7 (XCD), jj=s>>3, G=X*56+jj/6 (n,b group), mt=jj%6.
    const int s  = blockIdx.x;
    const int X  = s & 7, jj = s >> 3;
    const int G  = X * 56 + jj / 6;             // (n,b) group in [0,448)
    const int mt = jj % 6;
    const int nt = G % 7;
    const int b  = G / 7;

    const int m0   = mt * 128;
    const int n0   = nt * 128;
    const int mw   = wave & 1, nw = wave >> 1;  // 2x2 wave grid of 64x64 tiles
    const int lrow = lane & 15, lkc = lane >> 4;  // fragment row / k-chunk

    f32x4 acc[4][4] = {};
    const bf16* xb = xT + (size_t)b * (HWH * 256);

    for (int k0 = 0; k0 < 256; k0 += 32) {
#pragma unroll
        for (int i = 0; i < 2; ++i) {
            const int jb = 2 * wave + i;        // fragment-block (16 rows)
            const bf16* ga = wbf + (size_t)(m0 + 16 * jb + lrow) * 256 + k0 + lkc * 8;
            load_lds16(ga, &lds[jb * 512]);
            int n = n0 + 16 * jb + lrow;
            if (n > HWH - 1) n = HWH - 1;       // clamp: OOB cols never stored
            const bf16* gb = xb + (size_t)n * 256 + k0 + lkc * 8;
            load_lds16(gb, &lds[4096 + jb * 512]);
        }
        __syncthreads();

        frag8 af[4], bf_[4];
#pragma unroll
        for (int i = 0; i < 4; ++i)
            af[i] = *reinterpret_cast<const frag8*>(&lds[(4 * mw + i) * 512 + lane * 8]);
#pragma unroll
        for (int j2 = 0; j2 < 4; ++j2)
            bf_[j2] = *reinterpret_cast<const frag8*>(&lds[4096 + (4 * nw + j2) * 512 + lane * 8]);
#pragma unroll
        for (int i = 0; i < 4; ++i)
#pragma unroll
            for (int j2 = 0; j2 < 4; ++j2)
                acc[i][j2] = __builtin_amdgcn_mfma_f32_16x16x32_bf16(
                    af[i], bf_[j2], acc[i][j2], 0, 0, 0);
        __syncthreads();
    }

    // Epilogue: C/D layout col=lane&15 (n), row=(lane>>4)*4+reg (m)
    // Store into padded plane position (y+1)*30 + (x+1) = col + 2*(col/28) + 31
#pragma unroll
    for (int i = 0; i < 4; ++i) {
        const int rowb = m0 + mw * 64 + i * 16 + lkc * 4;
        bf16* base[4]; float bias4[4];
#pragma unroll
        for (int r = 0; r < 4; ++r) {
            const int m = rowb + r;
            const int sec = m >> 8, ch = m & 255;
            base[r] = perm + ((size_t)b * 64 + (ch & 63)) * PBLK
                           + (size_t)(sec * 4 + (ch >> 6)) * PPLANE;
            bias4[r] = biascat[m];
        }
#pragma unroll
        for (int j2 = 0; j2 < 4; ++j2) {
            const int col = n0 + nw * 64 + j2 * 16 + lrow;
            if (col < HWH) {
                const int pos = col + 2 * (col / 28) + 31;
#pragma unroll
                for (int r = 0; r < 4; ++r)
                    base[r][pos] = __float2bfloat16(acc[i][j2][r] + bias4[r]);
            }
        }
    }
}

// ---------------------------------------------------------------------------
// out_fused6: out = att + rate2 * conv, with att computed IN phase A from
// the x-window-means: attbs[oc][w] = rate1*(b3[4g+oc] + sum_c w3[4g+oc][c] *
// S'[b][w][c]). Eliminates the attmean kernel + its 29.5 MB perm re-read.
// Phase A: uint4 plane copy (21.6 KB) + weights + attbs dot (tid<100,
// float4 x 64 iters — hidden under the plane-copy load latency).
// Phase A2: zero halo borders. Phase C: 3x3 conv, 196 thr x 4 oc x 4 px,
// pitch 30 (bank stride 15). LDS ~24.3 KB -> 6 blocks/CU.
// VGPR history: (256,6) clamp -> spill catastrophe (R1); full c-unroll ->
// 256 VGPR spill (R2). Keep #pragma unroll 1 on the channel loop.
// ---------------------------------------------------------------------------
__global__ __launch_bounds__(256) void out_fused6(
    const bf16* __restrict__ perm, const float* __restrict__ W2,
    const float* __restrict__ sbar, const float* __restrict__ w3,
    const float* __restrict__ b3, const float* __restrict__ rate1,
    const float* __restrict__ rate2, float* __restrict__ out) {
    __shared__ __align__(16) short planes[12 * PPLANE];   // 21600 B, linear
    __shared__ float w2s[4][12][12];                      // [oc][c][k], k 9->12
    __shared__ float attbs[4][25];

    const int g = blockIdx.x, b = blockIdx.y, tid = threadIdx.x;

    // ---- phase A: linear LDS fill + attbs dot ----
    const uint4* src = (const uint4*)(perm + (size_t)(b * 64 + g) * PBLK);
#pragma unroll
    for (int it = 0; it < 6; ++it) {
        int e = tid + it * 256;                 // 1350 x 16B chunks
        if (e < 1350) ((uint4*)planes)[e] = src[e];
    }
    for (int e = tid; e < 576; e += 256) {
        int oc = e / 144, rem = e % 144, cc = rem / 12, k = rem % 12;
        w2s[oc][cc][k] = (k < 9) ? W2[(4 * g + oc) * 108 + cc * 9 + k] : 0.f;
    }
    if (tid < 100) {
        const int w = tid >> 2, oc = tid & 3;   // 4 oc share each w-row
        const float4* sv = (const float4*)(sbar + ((size_t)b * 25 + w) * 256);
        const float4* wv = (const float4*)(w3 + (size_t)(4 * g + oc) * 256);
        float s = 0.f;
#pragma unroll 8
        for (int i = 0; i < 64; ++i) {
            float4 a = sv[i], q = wv[i];
            s += a.x * q.x + a.y * q.y + a.z * q.z + a.w * q.w;
        }
        attbs[oc][w] = rate1[0] * (s + b3[4 * g + oc]);
    }
    __syncthreads();

    // ---- phase A2: zero halo borders (global borders hold garbage) ----
    for (int e = tid; e < 1392; e += 256) {
        int c12 = e / 116, u = e % 116, idx;
        if (u < 30)      idx = u;                         // top row
        else if (u < 60) idx = 870 + (u - 30);            // bottom row
        else { int v = u - 60; idx = ((v >> 1) + 1) * PPITCH + (v & 1) * 29; }
        planes[c12 * PPLANE + idx] = 0;
    }
    __syncthreads();

    // ---- phase C: conv. Lanes consecutive in y; bank stride 15 (odd). ----
    float acc[4][4] = {};   // [oc][px]
    const int y = tid % 28, xs = tid / 28, x0 = xs * 4;
    if (tid < 196) {
#pragma unroll 1   // CRITICAL: full unroll makes the scheduler hoist all 12
                   // channels' plane loads (~216 live floats) -> 256 VGPR + spill
        for (int c = 0; c < 12; ++c) {
            float rr[3][6];
#pragma unroll
            for (int dy = 0; dy < 3; ++dy) {
                const uint* row = (const uint*)&planes[c * PPLANE + (y + dy) * PPITCH + x0];
#pragma unroll
                for (int jp = 0; jp < 3; ++jp) {
                    uint w = row[jp];
                    float2 f = __bfloat1622float2(*(const __hip_bfloat162*)&w);
                    rr[dy][2 * jp]     = f.x;
                    rr[dy][2 * jp + 1] = f.y;
                }
            }
#pragma unroll
            for (int oc = 0; oc < 4; ++oc) {
                const float4* wr = reinterpret_cast<const float4*>(&w2s[oc][c][0]);
                float4 wa = wr[0], wb = wr[1], wc = wr[2];
                const float wk[9] = {wa.x, wa.y, wa.z, wa.w, wb.x, wb.y, wb.z, wb.w, wc.x};
#pragma unroll
                for (int ky = 0; ky < 3; ++ky)
#pragma unroll
                    for (int kx = 0; kx < 3; ++kx) {
                        float wv = wk[ky * 3 + kx];
#pragma unroll
                        for (int px = 0; px < 4; ++px)
                            acc[oc][px] += wv * rr[ky][px + kx];
                    }
            }
        }

        // ---- phase D: combine + store ----
        const float r2 = rate2[0];
        const int wi = (y >> 2) - 1, wj = xs - 1;
        const bool inter = (wi >= 0) & (wi < 5) & (wj >= 0) & (wj < 5);
#pragma unroll
        for (int oc = 0; oc < 4; ++oc) {
            float av = inter ? attbs[oc][wi * 5 + wj] : 0.f;
            float4 o;
            o.x = av + r2 * acc[oc][0];
            o.y = av + r2 * acc[oc][1];
            o.z = av + r2 * acc[oc][2];
            o.w = av + r2 * acc[oc][3];
            *reinterpret_cast<float4*>(
                &out[((size_t)(b * 256 + 4 * g + oc)) * HWH + y * 28 + x0]) = o;
        }
    }
}

// ---------------------------------------------------------------------------
extern "C" void kernel_launch(void* const* d_in, const int* in_sizes, int n_in,
                              void* d_out, int out_size, void* d_ws, size_t ws_size,
                              hipStream_t stream) {
    const float* x     = (const float*)d_in[0];
    const float* w1    = (const float*)d_in[1];
    const float* b1    = (const float*)d_in[2];
    const float* w2    = (const float*)d_in[3];
    const float* b2    = (const float*)d_in[4];
    const float* w3    = (const float*)d_in[5];
    const float* b3    = (const float*)d_in[6];
    const float* fc_w  = (const float*)d_in[7];
    const float* dep_w = (const float*)d_in[8];
    // d_in[9]/d_in[10] = rel_height/rel_width: provably dead (mask collapse)
    const float* rate1 = (const float*)d_in[11];
    const float* rate2 = (const float*)d_in[12];
    float* out = (float*)d_out;

    // workspace layout (bytes):
    //   perm    [0, 88473600)          64*64*12*900*2 (PADDED planes)
    //   xT      [88473600, 114163712)  64*784*256*2
    //   wbf     [114163712, 114556928) 768*256*2
    //   W2      [114556928, 114667520) 256*108*4
    //   biascat [114667520, 114670592) 768*4
    //   sbar    [114670592, 116308992) 64*25*256*4 (x window means, w-major)
    char* wsb = (char*)d_ws;
    bf16*  perm    = (bf16*)wsb;
    bf16*  xT      = (bf16*)(wsb + 88473600);
    bf16*  wbf     = (bf16*)(wsb + 114163712);
    float* W2      = (float*)(wsb + 114556928);
    float* biascat = (float*)(wsb + 114667520);
    float* sbar    = (float*)(wsb + 114670592);

    prep      <<<dim3(17772),      dim3(256), 0, stream>>>(x, w1, w2, w3, b1, b2, b3,
                                                           fc_w, dep_w, xT, wbf, W2,
                                                           biascat, sbar);
    gemm_mfma <<<dim3(2688),       dim3(256), 0, stream>>>(wbf, biascat, xT, perm);
    out_fused6<<<dim3(64, 64),     dim3(256), 0, stream>>>(perm, W2, sbar, w3, b3,
                                                           rate1, rate2, out);
}

// Round 14
// 268.235 us; speedup vs baseline: 1.0580x; 1.0580x over previous
//
#include <hip/hip_runtime.h>
#include <hip/hip_bf16.h>

typedef __hip_bfloat16 bf16;
typedef unsigned int uint;
typedef unsigned short ushort;

using frag8 = __attribute__((ext_vector_type(8))) short;   // 8 bf16
using f32x4 = __attribute__((ext_vector_type(4))) float;

#define HWH 784     // 28*28
#define PPITCH 30   // padded plane pitch (shorts)
#define PPLANE 900  // 30*30 shorts per plane
#define PBLK 10800  // 12*900 shorts per (b,g)

// ---------------------------------------------------------------------------
// prep: merged fold_w2 + wprep + xpose + xwinsum. 1-D grid, block ranges:
//   [0, 12800)      xpose   (25 n-tiles x 8 c-tiles x 64 b)
//   [12800, 13568)  wprep   (768 rows)
//   [13568, 13676)  fold_w2 (108 blocks x 256)
//   [13676, 17772)  xwinsum (64 b x 64 cg): S'[b][w][c] = interior 12x12
//                   window MEAN of x (pre-scaled 1/144). Attention identity:
//                   window-mean(v) = W3*window-mean(x) + b3 (linear map
//                   commutes with uniform mean; interior windows lie fully
//                   inside the image).
// ---------------------------------------------------------------------------
__global__ __launch_bounds__(256) void prep(const float* __restrict__ x,
                                            const float* __restrict__ w1,
                                            const float* __restrict__ w2,
                                            const float* __restrict__ w3,
                                            const float* __restrict__ b1,
                                            const float* __restrict__ b2,
                                            const float* __restrict__ b3,
                                            const float* __restrict__ fc_w,
                                            const float* __restrict__ dep_w,
                                            bf16* __restrict__ xT,
                                            bf16* __restrict__ wbf,
                                            float* __restrict__ W2,
                                            float* __restrict__ biascat,
                                            float* __restrict__ sbar) {
    __shared__ float t[32][33];
    const int bid = blockIdx.x, tid = threadIdx.x;

    if (bid < 12800) {
        // ---- xpose: x [b][c][n] f32 -> xT [b][n][c] bf16 (32x32 LDS tiles)
        const int n0 = (bid % 25) * 32;
        const int c0 = ((bid / 25) % 8) * 32;
        const int b  = bid / 200;
        const float* xb = x + (size_t)b * (256 * HWH);
#pragma unroll
        for (int e = tid; e < 1024; e += 256) {
            int r = e >> 5, col = e & 31;       // r: c-index, col: n-index
            int n = n0 + col;
            t[r][col] = (n < HWH) ? xb[(size_t)(c0 + r) * HWH + n] : 0.f;
        }
        __syncthreads();
#pragma unroll
        for (int e = tid; e < 512; e += 256) {
            int r = e >> 4, cp = (e & 15) * 2;  // r: n-index, cp: c-pair
            int n = n0 + r;
            if (n < HWH) {
                __hip_bfloat162 h;
                h.x = __float2bfloat16(t[cp][r]);
                h.y = __float2bfloat16(t[cp + 1][r]);
                *reinterpret_cast<__hip_bfloat162*>(
                    &xT[((size_t)b * HWH + n) * 256 + c0 + cp]) = h;
            }
        }
        return;
    }

    if (bid < 13568) {
        // ---- wprep: weights f32 -> bf16, concatenated [768][256]
        const int row = bid - 12800;
        const float* src = row < 256 ? w1 : (row < 512 ? w2 : w3);
        wbf[row * 256 + tid] = __float2bfloat16(src[(row & 255) * 256 + tid]);
        return;
    }

    if (bid < 13676) {
        // ---- fold_w2: W2[oc][c12][k9] = sum_o fc_w[o][c12]*dep_w[oc][o][k9]
        int idx = (bid - 13568) * 256 + tid;
        if (idx < 768) {
            const float* bs = idx < 256 ? b1 : (idx < 512 ? b2 : b3);
            biascat[idx] = bs[idx & 255];
        }
        if (idx >= 256 * 108) return;
        int oc  = idx / 108;
        int r   = idx % 108;
        int c12 = r / 9;
        int k9  = r % 9;
        float s = 0.f;
#pragma unroll
        for (int o = 0; o < 9; ++o)
            s += fc_w[o * 12 + c12] * dep_w[oc * 81 + o * 9 + k9];
        W2[idx] = s;
        return;
    }

    // ---- xwinsum: wave per channel; lanes 0..27 own columns
    {
        const int q  = bid - 13676;
        const int b  = q >> 6, cg = q & 63;
        const int wave = tid >> 6, lane = tid & 63;
        const int c  = cg * 4 + wave;                     // channel 0..255
        const float* xp = x + ((size_t)b * 256 + c) * HWH;

        float cs[5] = {0.f, 0.f, 0.f, 0.f, 0.f};          // per-wi column sums
        if (lane < 28) {
#pragma unroll
            for (int y = 0; y < 28; ++y) {
                float v = xp[y * 28 + lane];
#pragma unroll
                for (int wi = 0; wi < 5; ++wi)
                    if (y >= 4 * wi && y <= 4 * wi + 11) cs[wi] += v;
            }
        }
#pragma unroll
        for (int wi = 0; wi < 5; ++wi) {
            float p = cs[wi];
#pragma unroll
            for (int d = 1; d < 32; d <<= 1) {            // inclusive prefix
                float t2 = __shfl_up(p, d);
                if (lane >= d) p += t2;
            }
            float hi = __shfl(p, 4 * lane + 11);          // valid for lane<5
            float lo = __shfl(p, 4 * lane - 1);
            if (lane < 5) {
                float w = hi - (lane ? lo : 0.f);
                // S'[b][w][c], w-major rows of 256 floats
                sbar[((size_t)b * 25 + wi * 5 + lane) * 256 + c] =
                    w * (1.0f / 144.0f);
            }
        }
    }
}

// ---------------------------------------------------------------------------
// attdot: attm[(b*256+oc)*25+w] = rate1*(b3[oc] + sum_c w3[oc][c]*S'[b][w][c])
// Replaces attmean (which re-read 29.5 MB of perm and depended on gemm);
// attdot reads 1.6 MB of sbar and depends only on prep.
// ISOLATED KERNEL on purpose: R12 folded this dot into out_fused and the
// compiler clamped the whole kernel to 40 VGPR -> phase-C spills, 104 us
// (rule #19 regalloc perturbation). Grid (64 b x 4 w-quarters); 7 static
// accumulators/thread (~20 VGPR); 7 KB LDS.
// ---------------------------------------------------------------------------
__global__ __launch_bounds__(256) void attdot(const float* __restrict__ sbar,
                                              const float* __restrict__ w3,
                                              const float* __restrict__ b3,
                                              const float* __restrict__ rate1,
                                              float* __restrict__ attm) {
    __shared__ float s[7][256];                 // this block's 7 w-rows
    const int b = blockIdx.x, wq = blockIdx.y, tid = threadIdx.x;
    const int w0 = wq * 7;                      // w in [w0, min(w0+7, 25))

    for (int e = tid; e < 1792; e += 256) {
        int w = w0 + (e >> 8);
        ((float*)s)[e] = (w < 25) ? sbar[(size_t)b * 6400 + (size_t)w * 256 + (e & 255)] : 0.f;
    }
    __syncthreads();

    const float4* wrow = (const float4*)(w3 + (size_t)tid * 256);
    float acc[7] = {0.f, 0.f, 0.f, 0.f, 0.f, 0.f, 0.f};
#pragma unroll 4
    for (int i = 0; i < 64; ++i) {
        float4 q = wrow[i];
#pragma unroll
        for (int ws = 0; ws < 7; ++ws) {
            const float* sr = &s[ws][i * 4];
            acc[ws] += q.x * sr[0] + q.y * sr[1] + q.z * sr[2] + q.w * sr[3];
        }
    }
    const float r1 = rate1[0], bb = b3[tid];
#pragma unroll
    for (int ws = 0; ws < 7; ++ws) {
        int w = w0 + ws;
        if (w < 25)
            attm[((size_t)b * 256 + tid) * 25 + w] = r1 * (acc[ws] + bb);
    }
}

// ---------------------------------------------------------------------------
// MFMA GEMM (R6 verbatim, the benched best: 68 us):
// 128x128 tile, 2x2 wave grid, 16 KB LDS, 2 barriers/K-step, flat grid 2688
// with XCD-aware decode (FETCH 79->14 MB).
// K-loop surgery scoreboard (all on this structure, all LOST):
//   B-once 6mt/block 86us (R4) | B-once+prefetch 83us (R5) | dbuf 73us (R8)
//   | BK=64 84us (R9) | wave-private+vmcnt(0) 110us (R10) | operand-swap
//   neutral but pitch-34 slowed downstream (R7).
// Verdict: structural at HIP source on this problem size. DO NOT revisit.
// perm output: PADDED pitch-30 planes, image (y,x) at (y+1)*30+x+1; borders
// garbage, consumers zero halo in LDS.
// m -> sec=m/256, ch=m%256, g=ch%64, head=ch/64, t=sec*4+head.
// ---------------------------------------------------------------------------
__device__ inline void load_lds16(const bf16* g, short* lds) {
    __builtin_amdgcn_global_load_lds(
        (const __attribute__((address_space(1))) void*)g,
        (__attribute__((address_space(3))) void*)lds, 16, 0, 0);
}

__global__ __launch_bounds__(256) void gemm_mfma(const bf16* __restrict__ wbf,
                                                 const float* __restrict__ biascat,
                                                 const bf16* __restrict__ xT,
                                                 bf16* __restrict__ perm) {
    __shared__ short lds[8192];                 // A: [0,4096) shorts, B: [4096,8192)

    const int tid  = threadIdx.x;
    const int wave = tid >> 6, lane = tid & 63;

    // XCD-aware decode: X=s&7 (XCD), jj=s>>3, G=X*56+jj/6 (n,b group), mt=jj%6.
    const int s  = blockIdx.x;
    const int X  = s & 7, jj = s >> 3;
    const int G  = X * 56 + jj / 6;             // (n,b) group in [0,448)
    const int mt = jj % 6;
    const int nt = G % 7;
    const int b  = G / 7;

    const int m0   = mt * 128;
    const int n0   = nt * 128;
    const int mw   = wave & 1, nw = wave >> 1;  // 2x2 wave grid of 64x64 tiles
    const int lrow = lane & 15, lkc = lane >> 4;  // fragment row / k-chunk

    f32x4 acc[4][4] = {};
    const bf16* xb = xT + (size_t)b * (HWH * 256);

    for (int k0 = 0; k0 < 256; k0 += 32) {
#pragma unroll
        for (int i = 0; i < 2; ++i) {
            const int jb = 2 * wave + i;        // fragment-block (16 rows)
            const bf16* ga = wbf + (size_t)(m0 + 16 * jb + lrow) * 256 + k0 + lkc * 8;
            load_lds16(ga, &lds[jb * 512]);
            int n = n0 + 16 * jb + lrow;
            if (n > HWH - 1) n = HWH - 1;       // clamp: OOB cols never stored
            const bf16* gb = xb + (size_t)n * 256 + k0 + lkc * 8;
            load_lds16(gb, &lds[4096 + jb * 512]);
        }
        __syncthreads();

        frag8 af[4], bf_[4];
#pragma unroll
        for (int i = 0; i < 4; ++i)
            af[i] = *reinterpret_cast<const frag8*>(&lds[(4 * mw + i) * 512 + lane * 8]);
#pragma unroll
        for (int j2 = 0; j2 < 4; ++j2)
            bf_[j2] = *reinterpret_cast<const frag8*>(&lds[4096 + (4 * nw + j2) * 512 + lane * 8]);
#pragma unroll
        for (int i = 0; i < 4; ++i)
#pragma unroll
            for (int j2 = 0; j2 < 4; ++j2)
                acc[i][j2] = __builtin_amdgcn_mfma_f32_16x16x32_bf16(
                    af[i], bf_[j2], acc[i][j2], 0, 0, 0);
        __syncthreads();
    }

    // Epilogue: C/D layout col=lane&15 (n), row=(lane>>4)*4+reg (m)
    // Store into padded plane position (y+1)*30 + (x+1) = col + 2*(col/28) + 31
#pragma unroll
    for (int i = 0; i < 4; ++i) {
        const int rowb = m0 + mw * 64 + i * 16 + lkc * 4;
        bf16* base[4]; float bias4[4];
#pragma unroll
        for (int r = 0; r < 4; ++r) {
            const int m = rowb + r;
            const int sec = m >> 8, ch = m & 255;
            base[r] = perm + ((size_t)b * 64 + (ch & 63)) * PBLK
                           + (size_t)(sec * 4 + (ch >> 6)) * PPLANE;
            bias4[r] = biascat[m];
        }
#pragma unroll
        for (int j2 = 0; j2 < 4; ++j2) {
            const int col = n0 + nw * 64 + j2 * 16 + lrow;
            if (col < HWH) {
                const int pos = col + 2 * (col / 28) + 31;
#pragma unroll
                for (int r = 0; r < 4; ++r)
                    base[r][pos] = __float2bfloat16(acc[i][j2][r] + bias4[r]);
            }
        }
    }
}

// ---------------------------------------------------------------------------
// out_fused5 (R11 VERBATIM — proven <68 us): out = attm + rate2 * conv.
// Phase A: uint4 plane copy (21.6 KB) + weights + attm load (precomputed).
// Phase A2: zero halo borders. Phase C: 3x3 conv, 196 thr x 4 oc x 4 px,
// pitch 30 (bank stride 15). LDS ~24.3 KB -> 6 blocks/CU.
// DO NOT add code to this kernel: R12 folded the attbs dot into phase A and
// the compiler clamped VGPR to 40 -> phase-C spills -> 104 us. Keep the dot
// in attdot. Keep #pragma unroll 1 on the channel loop (R2: full unroll ->
// 256 VGPR spill). No launch-bounds min-waves (R1: (256,6) -> 40 VGPR).
// ---------------------------------------------------------------------------
__global__ __launch_bounds__(256) void out_fused5(
    const bf16* __restrict__ perm, const float* __restrict__ W2,
    const float* __restrict__ attm, const float* __restrict__ rate2,
    float* __restrict__ out) {
    __shared__ __align__(16) short planes[12 * PPLANE];   // 21600 B, linear
    __shared__ float w2s[4][12][12];                      // [oc][c][k], k 9->12
    __shared__ float attbs[4][25];

    const int g = blockIdx.x, b = blockIdx.y, tid = threadIdx.x;

    // ---- phase A: linear LDS fill ----
    const uint4* src = (const uint4*)(perm + (size_t)(b * 64 + g) * PBLK);
#pragma unroll
    for (int it = 0; it < 6; ++it) {
        int e = tid + it * 256;                 // 1350 x 16B chunks
        if (e < 1350) ((uint4*)planes)[e] = src[e];
    }
    for (int e = tid; e < 576; e += 256) {
        int oc = e / 144, rem = e % 144, cc = rem / 12, k = rem % 12;
        w2s[oc][cc][k] = (k < 9) ? W2[(4 * g + oc) * 108 + cc * 9 + k] : 0.f;
    }
    if (tid < 100)
        attbs[tid / 25][tid % 25] =
            attm[((size_t)b * 256 + 4 * g + tid / 25) * 25 + tid % 25];
    __syncthreads();

    // ---- phase A2: zero halo borders (global borders hold garbage) ----
    for (int e = tid; e < 1392; e += 256) {
        int c12 = e / 116, u = e % 116, idx;
        if (u < 30)      idx = u;                         // top row
        else if (u < 60) idx = 870 + (u - 30);            // bottom row
        else { int v = u - 60; idx = ((v >> 1) + 1) * PPITCH + (v & 1) * 29; }
        planes[c12 * PPLANE + idx] = 0;
    }
    __syncthreads();

    // ---- phase C: conv. Lanes consecutive in y; bank stride 15 (odd). ----
    float acc[4][4] = {};   // [oc][px]
    const int y = tid % 28, xs = tid / 28, x0 = xs * 4;
    if (tid < 196) {
#pragma unroll 1   // CRITICAL: full unroll makes the scheduler hoist all 12
                   // channels' plane loads (~216 live floats) -> 256 VGPR + spill
        for (int c = 0; c < 12; ++c) {
            float rr[3][6];
#pragma unroll
            for (int dy = 0; dy < 3; ++dy) {
                const uint* row = (const uint*)&planes[c * PPLANE + (y + dy) * PPITCH + x0];
#pragma unroll
                for (int jp = 0; jp < 3; ++jp) {
                    uint w = row[jp];
                    float2 f = __bfloat1622float2(*(const __hip_bfloat162*)&w);
                    rr[dy][2 * jp]     = f.x;
                    rr[dy][2 * jp + 1] = f.y;
                }
            }
#pragma unroll
            for (int oc = 0; oc < 4; ++oc) {
                const float4* wr = reinterpret_cast<const float4*>(&w2s[oc][c][0]);
                float4 wa = wr[0], wb = wr[1], wc = wr[2];
                const float wk[9] = {wa.x, wa.y, wa.z, wa.w, wb.x, wb.y, wb.z, wb.w, wc.x};
#pragma unroll
                for (int ky = 0; ky < 3; ++ky)
#pragma unroll
                    for (int kx = 0; kx < 3; ++kx) {
                        float wv = wk[ky * 3 + kx];
#pragma unroll
                        for (int px = 0; px < 4; ++px)
                            acc[oc][px] += wv * rr[ky][px + kx];
                    }
            }
        }

        // ---- phase D: combine + store ----
        const float r2 = rate2[0];
        const int wi = (y >> 2) - 1, wj = xs - 1;
        const bool inter = (wi >= 0) & (wi < 5) & (wj >= 0) & (wj < 5);
#pragma unroll
        for (int oc = 0; oc < 4; ++oc) {
            float av = inter ? attbs[oc][wi * 5 + wj] : 0.f;
            float4 o;
            o.x = av + r2 * acc[oc][0];
            o.y = av + r2 * acc[oc][1];
            o.z = av + r2 * acc[oc][2];
            o.w = av + r2 * acc[oc][3];
            *reinterpret_cast<float4*>(
                &out[((size_t)(b * 256 + 4 * g + oc)) * HWH + y * 28 + x0]) = o;
        }
    }
}

// ---------------------------------------------------------------------------
extern "C" void kernel_launch(void* const* d_in, const int* in_sizes, int n_in,
                              void* d_out, int out_size, void* d_ws, size_t ws_size,
                              hipStream_t stream) {
    const float* x     = (const float*)d_in[0];
    const float* w1    = (const float*)d_in[1];
    const float* b1    = (const float*)d_in[2];
    const float* w2    = (const float*)d_in[3];
    const float* b2    = (const float*)d_in[4];
    const float* w3    = (const float*)d_in[5];
    const float* b3    = (const float*)d_in[6];
    const float* fc_w  = (const float*)d_in[7];
    const float* dep_w = (const float*)d_in[8];
    // d_in[9]/d_in[10] = rel_height/rel_width: provably dead (mask collapse)
    const float* rate1 = (const float*)d_in[11];
    const float* rate2 = (const float*)d_in[12];
    float* out = (float*)d_out;

    // workspace layout (bytes):
    //   perm    [0, 88473600)          64*64*12*900*2 (PADDED planes)
    //   xT      [88473600, 114163712)  64*784*256*2
    //   wbf     [114163712, 114556928) 768*256*2
    //   W2      [114556928, 114667520) 256*108*4
    //   biascat [114667520, 114670592) 768*4
    //   sbar    [114670592, 116308992) 64*25*256*4 (x window means, w-major)
    //   attm    [116308992, 117947392) 64*256*25*4
    char* wsb = (char*)d_ws;
    bf16*  perm    = (bf16*)wsb;
    bf16*  xT      = (bf16*)(wsb + 88473600);
    bf16*  wbf     = (bf16*)(wsb + 114163712);
    float* W2      = (float*)(wsb + 114556928);
    float* biascat = (float*)(wsb + 114667520);
    float* sbar    = (float*)(wsb + 114670592);
    float* attm    = (float*)(wsb + 116308992);

    prep      <<<dim3(17772),      dim3(256), 0, stream>>>(x, w1, w2, w3, b1, b2, b3,
                                                           fc_w, dep_w, xT, wbf, W2,
                                                           biascat, sbar);
    attdot    <<<dim3(64, 4),      dim3(256), 0, stream>>>(sbar, w3, b3, rate1, attm);
    gemm_mfma <<<dim3(2688),       dim3(256), 0, stream>>>(wbf, biascat, xT, perm);
    out_fused5<<<dim3(64, 64),     dim3(256), 0, stream>>>(perm, W2, attm, rate2, out);
}

// Round 15
// 248.117 us; speedup vs baseline: 1.1437x; 1.0811x over previous
//
#include <hip/hip_runtime.h>
#include <hip/hip_bf16.h>

typedef __hip_bfloat16 bf16;
typedef unsigned int uint;
typedef unsigned short ushort;

using frag8 = __attribute__((ext_vector_type(8))) short;   // 8 bf16
using f32x4 = __attribute__((ext_vector_type(4))) float;

#define HWH 784     // 28*28
#define PPITCH 30   // padded plane pitch (shorts)
#define PPLANE 900  // 30*30 shorts per plane
#define PBLK 10800  // 12*900 shorts per (b,g)

// ---------------------------------------------------------------------------
// prep: merged fold_w2 + wprep + xpose. 1-D grid, decoded by block range:
//   [0, 12800)      xpose   (25 n-tiles x 8 c-tiles x 64 b)
//   [12800, 13568)  wprep   (768 rows)
//   [13568, 13676)  fold_w2 (108 blocks x 256)
// R14 lesson: do NOT add xwinsum here — the x-window-mean + attdot path
// (algebraically exact) measured +17 us vs attmean: attmean's perm read is
// L3-resident (perm just written by gemm) and nearly free, while xwinsum's
// 28-lane scalar reads re-pull 51 MB of x at poor coalescing.
// ---------------------------------------------------------------------------
__global__ __launch_bounds__(256) void prep(const float* __restrict__ x,
                                            const float* __restrict__ w1,
                                            const float* __restrict__ w2,
                                            const float* __restrict__ w3,
                                            const float* __restrict__ b1,
                                            const float* __restrict__ b2,
                                            const float* __restrict__ b3,
                                            const float* __restrict__ fc_w,
                                            const float* __restrict__ dep_w,
                                            bf16* __restrict__ xT,
                                            bf16* __restrict__ wbf,
                                            float* __restrict__ W2,
                                            float* __restrict__ biascat) {
    __shared__ float t[32][33];
    const int bid = blockIdx.x, tid = threadIdx.x;

    if (bid < 12800) {
        // ---- xpose: x [b][c][n] f32 -> xT [b][n][c] bf16 (32x32 LDS tiles)
        const int n0 = (bid % 25) * 32;
        const int c0 = ((bid / 25) % 8) * 32;
        const int b  = bid / 200;
        const float* xb = x + (size_t)b * (256 * HWH);
#pragma unroll
        for (int e = tid; e < 1024; e += 256) {
            int r = e >> 5, col = e & 31;       // r: c-index, col: n-index
            int n = n0 + col;
            t[r][col] = (n < HWH) ? xb[(size_t)(c0 + r) * HWH + n] : 0.f;
        }
        __syncthreads();
#pragma unroll
        for (int e = tid; e < 512; e += 256) {
            int r = e >> 4, cp = (e & 15) * 2;  // r: n-index, cp: c-pair
            int n = n0 + r;
            if (n < HWH) {
                __hip_bfloat162 h;
                h.x = __float2bfloat16(t[cp][r]);
                h.y = __float2bfloat16(t[cp + 1][r]);
                *reinterpret_cast<__hip_bfloat162*>(
                    &xT[((size_t)b * HWH + n) * 256 + c0 + cp]) = h;
            }
        }
        return;
    }

    if (bid < 13568) {
        // ---- wprep: weights f32 -> bf16, concatenated [768][256]
        const int row = bid - 12800;
        const float* src = row < 256 ? w1 : (row < 512 ? w2 : w3);
        wbf[row * 256 + tid] = __float2bfloat16(src[(row & 255) * 256 + tid]);
        return;
    }

    // ---- fold_w2: W2[oc][c12][k9] = sum_o fc_w[o][c12]*dep_w[oc][o][k9]
    int idx = (bid - 13568) * 256 + tid;
    if (idx < 768) {
        const float* bs = idx < 256 ? b1 : (idx < 512 ? b2 : b3);
        biascat[idx] = bs[idx & 255];
    }
    if (idx >= 256 * 108) return;
    int oc  = idx / 108;
    int r   = idx % 108;
    int c12 = r / 9;
    int k9  = r % 9;
    float s = 0.f;
#pragma unroll
    for (int o = 0; o < 9; ++o)
        s += fc_w[o * 12 + c12] * dep_w[oc * 81 + o * 9 + k9];
    W2[idx] = s;
}

// ---------------------------------------------------------------------------
// MFMA GEMM (R6 verbatim — session-best 68 us):
// 128x128 tile, 2x2 wave grid, 16 KB LDS, 2 barriers/K-step, flat grid 2688
// with XCD-aware decode (FETCH 79->14 MB).
// K-loop surgery scoreboard (all on this structure, all LOST):
//   B-once 6mt/block 86us (R4) | B-once+prefetch 83us (R5) | dbuf 73us (R8:
//   __syncthreads == s_waitcnt vmcnt(0)+s_barrier drains same-step prefetch)
//   | BK=64 84us (R9: 32KB LDS halves residency) | wave-private vmcnt(0)
//   110us (R10: full latency on each wave's serial path) | operand-swap
//   neutral, pitch-34 slowed downstream (R7).
// Verdict: structural at HIP source on this problem size. DO NOT revisit.
// perm output: PADDED pitch-30 planes, image (y,x) at (y+1)*30+x+1; borders
// garbage, consumers zero halo in LDS.
// m -> sec=m/256, ch=m%256, g=ch%64, head=ch/64, t=sec*4+head.
// ---------------------------------------------------------------------------
__device__ inline void load_lds16(const bf16* g, short* lds) {
    __builtin_amdgcn_global_load_lds(
        (const __attribute__((address_space(1))) void*)g,
        (__attribute__((address_space(3))) void*)lds, 16, 0, 0);
}

__global__ __launch_bounds__(256) void gemm_mfma(const bf16* __restrict__ wbf,
                                                 const float* __restrict__ biascat,
                                                 const bf16* __restrict__ xT,
                                                 bf16* __restrict__ perm) {
    __shared__ short lds[8192];                 // A: [0,4096) shorts, B: [4096,8192)

    const int tid  = threadIdx.x;
    const int wave = tid >> 6, lane = tid & 63;

    // XCD-aware decode: X=s&7 (XCD), jj=s>>3, G=X*56+jj/6 (n,b group), mt=jj%6.
    const int s  = blockIdx.x;
    const int X  = s & 7, jj = s >> 3;
    const int G  = X * 56 + jj / 6;             // (n,b) group in [0,448)
    const int mt = jj % 6;
    const int nt = G % 7;
    const int b  = G / 7;

    const int m0   = mt * 128;
    const int n0   = nt * 128;
    const int mw   = wave & 1, nw = wave >> 1;  // 2x2 wave grid of 64x64 tiles
    const int lrow = lane & 15, lkc = lane >> 4;  // fragment row / k-chunk

    f32x4 acc[4][4] = {};
    const bf16* xb = xT + (size_t)b * (HWH * 256);

    for (int k0 = 0; k0 < 256; k0 += 32) {
#pragma unroll
        for (int i = 0; i < 2; ++i) {
            const int jb = 2 * wave + i;        // fragment-block (16 rows)
            const bf16* ga = wbf + (size_t)(m0 + 16 * jb + lrow) * 256 + k0 + lkc * 8;
            load_lds16(ga, &lds[jb * 512]);
            int n = n0 + 16 * jb + lrow;
            if (n > HWH - 1) n = HWH - 1;       // clamp: OOB cols never stored
            const bf16* gb = xb + (size_t)n * 256 + k0 + lkc * 8;
            load_lds16(gb, &lds[4096 + jb * 512]);
        }
        __syncthreads();

        frag8 af[4], bf_[4];
#pragma unroll
        for (int i = 0; i < 4; ++i)
            af[i] = *reinterpret_cast<const frag8*>(&lds[(4 * mw + i) * 512 + lane * 8]);
#pragma unroll
        for (int j2 = 0; j2 < 4; ++j2)
            bf_[j2] = *reinterpret_cast<const frag8*>(&lds[4096 + (4 * nw + j2) * 512 + lane * 8]);
#pragma unroll
        for (int i = 0; i < 4; ++i)
#pragma unroll
            for (int j2 = 0; j2 < 4; ++j2)
                acc[i][j2] = __builtin_amdgcn_mfma_f32_16x16x32_bf16(
                    af[i], bf_[j2], acc[i][j2], 0, 0, 0);
        __syncthreads();
    }

    // Epilogue: C/D layout col=lane&15 (n), row=(lane>>4)*4+reg (m)
    // Store into padded plane position (y+1)*30 + (x+1) = col + 2*(col/28) + 31
#pragma unroll
    for (int i = 0; i < 4; ++i) {
        const int rowb = m0 + mw * 64 + i * 16 + lkc * 4;
        bf16* base[4]; float bias4[4];
#pragma unroll
        for (int r = 0; r < 4; ++r) {
            const int m = rowb + r;
            const int sec = m >> 8, ch = m & 255;
            base[r] = perm + ((size_t)b * 64 + (ch & 63)) * PBLK
                           + (size_t)(sec * 4 + (ch >> 6)) * PPLANE;
            bias4[r] = biascat[m];
        }
#pragma unroll
        for (int j2 = 0; j2 < 4; ++j2) {
            const int col = n0 + nw * 64 + j2 * 16 + lrow;
            if (col < HWH) {
                const int pos = col + 2 * (col / 28) + 31;
#pragma unroll
                for (int r = 0; r < 4; ++r)
                    base[r][pos] = __float2bfloat16(acc[i][j2][r] + bias4[r]);
            }
        }
    }
}

// ---------------------------------------------------------------------------
// attmean: interior 12x12 window means of v, prescaled by rate1/144.
// attm[b][c][25] f32. One wave per channel; lanes 0..27 own columns.
// v channel c lives at perm[b][c&63][8 + c/64] (bias already included).
// KEEP THIS KERNEL: perm is L3-resident right after gemm writes it, so this
// read is nearly free. The algebraic replacement (x-window means + W3 dot,
// R12-R14) was exact but NET SLOWER (+17 us): xwinsum re-read 51 MB of x at
// 112 B/transaction, and folding the dot into out_fused clamped it to 40
// VGPR -> phase-C spill (104 us).
// ---------------------------------------------------------------------------
__global__ __launch_bounds__(256) void attmean(const bf16* __restrict__ perm,
                                               const float* __restrict__ rate1,
                                               float* __restrict__ attm) {
    const int b = blockIdx.y, cg = blockIdx.x;            // cg in [0,64)
    const int wave = threadIdx.x >> 6, lane = threadIdx.x & 63;
    const int c = cg * 4 + wave;                          // channel 0..255
    const bf16* vp = perm + ((size_t)(b * 64 + (c & 63)) * 12 + 8 + (c >> 6)) * (size_t)PPLANE;

    float cs[5] = {0.f, 0.f, 0.f, 0.f, 0.f};              // per-wi column sums
    if (lane < 28) {
#pragma unroll
        for (int y = 0; y < 28; ++y) {
            float v = __bfloat162float(vp[(y + 1) * PPITCH + lane + 1]);
#pragma unroll
            for (int wi = 0; wi < 5; ++wi)
                if (y >= 4 * wi && y <= 4 * wi + 11) cs[wi] += v;
        }
    }
    const float r1s = rate1[0] * (1.0f / 144.0f);
#pragma unroll
    for (int wi = 0; wi < 5; ++wi) {
        float p = cs[wi];
#pragma unroll
        for (int d = 1; d < 32; d <<= 1) {                // inclusive prefix over lanes
            float t = __shfl_up(p, d);
            if (lane >= d) p += t;
        }
        float hi = __shfl(p, 4 * lane + 11);              // valid for lane<5
        float lo = __shfl(p, 4 * lane - 1);
        if (lane < 5) {
            float w = hi - (lane ? lo : 0.f);
            attm[((size_t)b * 256 + c) * 25 + wi * 5 + lane] = w * r1s;
        }
    }
}

// ---------------------------------------------------------------------------
// out_fused5 (proven <68 us): out = attm + rate2 * conv.
// Phase A: uint4 plane copy (21.6 KB) + weights + attm load (precomputed).
// Phase A2: zero halo borders. Phase C: 3x3 conv, 196 thr x 4 oc x 4 px,
// pitch 30 (bank stride 15). LDS ~24.3 KB -> 6 blocks/CU.
// DO NOT add code to this kernel: R12 folded the attbs dot into phase A and
// the compiler clamped VGPR to 40 -> phase-C spills -> 104 us. Keep
// #pragma unroll 1 on the channel loop (R2: full unroll -> 256 VGPR spill).
// No launch-bounds min-waves (R1: (256,6) -> 40 VGPR catastrophe).
// ---------------------------------------------------------------------------
__global__ __launch_bounds__(256) void out_fused5(
    const bf16* __restrict__ perm, const float* __restrict__ W2,
    const float* __restrict__ attm, const float* __restrict__ rate2,
    float* __restrict__ out) {
    __shared__ __align__(16) short planes[12 * PPLANE];   // 21600 B, linear
    __shared__ float w2s[4][12][12];                      // [oc][c][k], k 9->12
    __shared__ float attbs[4][25];

    const int g = blockIdx.x, b = blockIdx.y, tid = threadIdx.x;

    // ---- phase A: linear LDS fill ----
    const uint4* src = (const uint4*)(perm + (size_t)(b * 64 + g) * PBLK);
#pragma unroll
    for (int it = 0; it < 6; ++it) {
        int e = tid + it * 256;                 // 1350 x 16B chunks
        if (e < 1350) ((uint4*)planes)[e] = src[e];
    }
    for (int e = tid; e < 576; e += 256) {
        int oc = e / 144, rem = e % 144, cc = rem / 12, k = rem % 12;
        w2s[oc][cc][k] = (k < 9) ? W2[(4 * g + oc) * 108 + cc * 9 + k] : 0.f;
    }
    if (tid < 100)
        attbs[tid / 25][tid % 25] =
            attm[((size_t)b * 256 + 4 * g + tid / 25) * 25 + tid % 25];
    __syncthreads();

    // ---- phase A2: zero halo borders (global borders hold garbage) ----
    for (int e = tid; e < 1392; e += 256) {
        int c12 = e / 116, u = e % 116, idx;
        if (u < 30)      idx = u;                         // top row
        else if (u < 60) idx = 870 + (u - 30);            // bottom row
        else { int v = u - 60; idx = ((v >> 1) + 1) * PPITCH + (v & 1) * 29; }
        planes[c12 * PPLANE + idx] = 0;
    }
    __syncthreads();

    // ---- phase C: conv. Lanes consecutive in y; bank stride 15 (odd). ----
    float acc[4][4] = {};   // [oc][px]
    const int y = tid % 28, xs = tid / 28, x0 = xs * 4;
    if (tid < 196) {
#pragma unroll 1   // CRITICAL: full unroll makes the scheduler hoist all 12
                   // channels' plane loads (~216 live floats) -> 256 VGPR + spill
        for (int c = 0; c < 12; ++c) {
            float rr[3][6];
#pragma unroll
            for (int dy = 0; dy < 3; ++dy) {
                const uint* row = (const uint*)&planes[c * PPLANE + (y + dy) * PPITCH + x0];
#pragma unroll
                for (int jp = 0; jp < 3; ++jp) {
                    uint w = row[jp];
                    float2 f = __bfloat1622float2(*(const __hip_bfloat162*)&w);
                    rr[dy][2 * jp]     = f.x;
                    rr[dy][2 * jp + 1] = f.y;
                }
            }
#pragma unroll
            for (int oc = 0; oc < 4; ++oc) {
                const float4* wr = reinterpret_cast<const float4*>(&w2s[oc][c][0]);
                float4 wa = wr[0], wb = wr[1], wc = wr[2];
                const float wk[9] = {wa.x, wa.y, wa.z, wa.w, wb.x, wb.y, wb.z, wb.w, wc.x};
#pragma unroll
                for (int ky = 0; ky < 3; ++ky)
#pragma unroll
                    for (int kx = 0; kx < 3; ++kx) {
                        float wv = wk[ky * 3 + kx];
#pragma unroll
                        for (int px = 0; px < 4; ++px)
                            acc[oc][px] += wv * rr[ky][px + kx];
                    }
            }
        }

        // ---- phase D: combine + store ----
        const float r2 = rate2[0];
        const int wi = (y >> 2) - 1, wj = xs - 1;
        const bool inter = (wi >= 0) & (wi < 5) & (wj >= 0) & (wj < 5);
#pragma unroll
        for (int oc = 0; oc < 4; ++oc) {
            float av = inter ? attbs[oc][wi * 5 + wj] : 0.f;
            float4 o;
            o.x = av + r2 * acc[oc][0];
            o.y = av + r2 * acc[oc][1];
            o.z = av + r2 * acc[oc][2];
            o.w = av + r2 * acc[oc][3];
            *reinterpret_cast<float4*>(
                &out[((size_t)(b * 256 + 4 * g + oc)) * HWH + y * 28 + x0]) = o;
        }
    }
}

// ---------------------------------------------------------------------------
extern "C" void kernel_launch(void* const* d_in, const int* in_sizes, int n_in,
                              void* d_out, int out_size, void* d_ws, size_t ws_size,
                              hipStream_t stream) {
    const float* x     = (const float*)d_in[0];
    const float* w1    = (const float*)d_in[1];
    const float* b1    = (const float*)d_in[2];
    const float* w2    = (const float*)d_in[3];
    const float* b2    = (const float*)d_in[4];
    const float* w3    = (const float*)d_in[5];
    const float* b3    = (const float*)d_in[6];
    const float* fc_w  = (const float*)d_in[7];
    const float* dep_w = (const float*)d_in[8];
    // d_in[9]/d_in[10] = rel_height/rel_width: provably dead (mask collapse)
    const float* rate1 = (const float*)d_in[11];
    const float* rate2 = (const float*)d_in[12];
    float* out = (float*)d_out;

    // workspace layout (bytes):
    //   perm    [0, 88473600)          64*64*12*900*2 (PADDED planes)
    //   xT      [88473600, 114163712)  64*784*256*2
    //   attm    = xT base (reused AFTER gemm consumes xT; stream-ordered)
    //   wbf     [114163712, 114556928) 768*256*2
    //   W2      [114556928, 114667520) 256*108*4
    //   biascat [114667520, 114670592) 768*4
    char* wsb = (char*)d_ws;
    bf16*  perm    = (bf16*)wsb;
    bf16*  xT      = (bf16*)(wsb + 88473600);
    float* attm    = (float*)(wsb + 88473600);           // alias of xT
    bf16*  wbf     = (bf16*)(wsb + 114163712);
    float* W2      = (float*)(wsb + 114556928);
    float* biascat = (float*)(wsb + 114667520);

    prep      <<<dim3(13676),      dim3(256), 0, stream>>>(x, w1, w2, w3, b1, b2, b3,
                                                           fc_w, dep_w, xT, wbf, W2, biascat);
    gemm_mfma <<<dim3(2688),       dim3(256), 0, stream>>>(wbf, biascat, xT, perm);
    attmean   <<<dim3(64, 64),     dim3(256), 0, stream>>>(perm, rate1, attm);
    out_fused5<<<dim3(64, 64),     dim3(256), 0, stream>>>(perm, W2, attm, rate2, out);
}

// Round 16
// 238.856 us; speedup vs baseline: 1.1881x; 1.0388x over previous
//
#include <hip/hip_runtime.h>
#include <hip/hip_bf16.h>

typedef __hip_bfloat16 bf16;
typedef unsigned int uint;
typedef unsigned short ushort;

using frag8 = __attribute__((ext_vector_type(8))) short;   // 8 bf16
using f32x4 = __attribute__((ext_vector_type(4))) float;

#define HWH 784     // 28*28
#define PPITCH 30   // padded plane pitch (shorts)
#define PPLANE 900  // 30*30 shorts per plane
#define PBLK 10800  // 12*900 shorts per (b,g)

// ---------------------------------------------------------------------------
// prep: merged fold_w2 + wprep + xpose. 1-D grid, decoded by block range:
//   [0, 3328)      xpose   (13 n-tiles x 4 c-tiles x 64 b, 64x64 tiles)
//   [3328, 4096)   wprep   (768 rows)
//   [4096, 4204)   fold_w2 (108 blocks x 256)
// R16: xpose VECTORIZED (Guideline 13). Old version: 4 B/lane scalar f32
// reads + 4 B bf162 stores, 12800 tiny blocks — est. ~60-70 us of the
// unaccounted ~80 us prologue budget (R0 arithmetic). New: 64x64 tiles,
// float4 reads (16 B/lane), uint4 bf16x8 stores (16 B/lane), LDS [64][65]
// f32 (odd pitch -> conflict-free column reads), 3328 blocks.
// Tail tile n>=768: float4 read column clamped to 780 (in-row, 16B-aligned;
// garbage lands only in unused t2 columns), stores guarded n<784.
// R14 lesson: do NOT add xwinsum here (attmean is cheaper — perm is
// L3-resident after gemm).
// ---------------------------------------------------------------------------
__global__ __launch_bounds__(256) void prep(const float* __restrict__ x,
                                            const float* __restrict__ w1,
                                            const float* __restrict__ w2,
                                            const float* __restrict__ w3,
                                            const float* __restrict__ b1,
                                            const float* __restrict__ b2,
                                            const float* __restrict__ b3,
                                            const float* __restrict__ fc_w,
                                            const float* __restrict__ dep_w,
                                            bf16* __restrict__ xT,
                                            bf16* __restrict__ wbf,
                                            float* __restrict__ W2,
                                            float* __restrict__ biascat) {
    __shared__ float t2[64][65];                // 16.6 KB, odd pitch
    const int bid = blockIdx.x, tid = threadIdx.x;

    if (bid < 3328) {
        // ---- xpose: x [b][c][n] f32 -> xT [b][n][c] bf16, 64x64 tile
        const int nt = bid % 13;
        const int ct = (bid / 13) & 3;
        const int b  = bid / 52;
        const int n0 = nt * 64, c0 = ct * 64;
        const float* xb = x + (size_t)b * (256 * HWH);

        // phase 1: float4 reads, coalesced along n
#pragma unroll
        for (int it = 0; it < 4; ++it) {
            const int e = tid + it * 256;       // [0,1024): 64 rows x 16 chunks
            const int r = e >> 4;               // c-index 0..63
            const int col4 = (e & 15) * 4;      // n-offset 0..60
            int nc = n0 + col4;
            if (nc > 780) nc = 780;             // tail clamp (in-row, aligned)
            const float4 q = *reinterpret_cast<const float4*>(
                &xb[(size_t)(c0 + r) * HWH + nc]);
            t2[r][col4]     = q.x;
            t2[r][col4 + 1] = q.y;
            t2[r][col4 + 2] = q.z;
            t2[r][col4 + 3] = q.w;
        }
        __syncthreads();

        // phase 2: 8 bf16 (16 B) stores, coalesced along c
#pragma unroll
        for (int it = 0; it < 2; ++it) {
            const int e2 = tid + it * 256;      // [0,512): 64 n x 8 c-chunks
            const int r2 = e2 >> 3;             // n-offset 0..63
            const int c8 = (e2 & 7) * 8;        // c-offset 0..56
            const int n  = n0 + r2;
            if (n < HWH) {
                uint pk[4];
#pragma unroll
                for (int j = 0; j < 4; ++j) {
                    __hip_bfloat162 h;
                    h.x = __float2bfloat16(t2[c8 + 2 * j][r2]);
                    h.y = __float2bfloat16(t2[c8 + 2 * j + 1][r2]);
                    pk[j] = *reinterpret_cast<uint*>(&h);
                }
                *reinterpret_cast<uint4*>(
                    &xT[((size_t)b * HWH + n) * 256 + c0 + c8]) =
                    *reinterpret_cast<uint4*>(pk);
            }
        }
        return;
    }

    if (bid < 4096) {
        // ---- wprep: weights f32 -> bf16, concatenated [768][256]
        const int row = bid - 3328;
        const float* src = row < 256 ? w1 : (row < 512 ? w2 : w3);
        wbf[row * 256 + tid] = __float2bfloat16(src[(row & 255) * 256 + tid]);
        return;
    }

    // ---- fold_w2: W2[oc][c12][k9] = sum_o fc_w[o][c12]*dep_w[oc][o][k9]
    int idx = (bid - 4096) * 256 + tid;
    if (idx < 768) {
        const float* bs = idx < 256 ? b1 : (idx < 512 ? b2 : b3);
        biascat[idx] = bs[idx & 255];
    }
    if (idx >= 256 * 108) return;
    int oc  = idx / 108;
    int r   = idx % 108;
    int c12 = r / 9;
    int k9  = r % 9;
    float s = 0.f;
#pragma unroll
    for (int o = 0; o < 9; ++o)
        s += fc_w[o * 12 + c12] * dep_w[oc * 81 + o * 9 + k9];
    W2[idx] = s;
}

// ---------------------------------------------------------------------------
// MFMA GEMM (R6 verbatim — session-best 68 us):
// 128x128 tile, 2x2 wave grid, 16 KB LDS, 2 barriers/K-step, flat grid 2688
// with XCD-aware decode (FETCH 79->14 MB).
// K-loop surgery scoreboard (all on this structure, all LOST):
//   B-once 6mt/block 86us (R4) | B-once+prefetch 83us (R5) | dbuf 73us (R8:
//   __syncthreads == s_waitcnt vmcnt(0)+s_barrier drains same-step prefetch)
//   | BK=64 84us (R9: 32KB LDS halves residency) | wave-private vmcnt(0)
//   110us (R10: full latency on each wave's serial path) | operand-swap
//   neutral, pitch-34 slowed downstream (R7).
// Verdict: structural at HIP source on this problem size. DO NOT revisit.
// perm output: PADDED pitch-30 planes, image (y,x) at (y+1)*30+x+1; borders
// garbage, consumers zero halo in LDS.
// m -> sec=m/256, ch=m%256, g=ch%64, head=ch/64, t=sec*4+head.
// ---------------------------------------------------------------------------
__device__ inline void load_lds16(const bf16* g, short* lds) {
    __builtin_amdgcn_global_load_lds(
        (const __attribute__((address_space(1))) void*)g,
        (__attribute__((address_space(3))) void*)lds, 16, 0, 0);
}

__global__ __launch_bounds__(256) void gemm_mfma(const bf16* __restrict__ wbf,
                                                 const float* __restrict__ biascat,
                                                 const bf16* __restrict__ xT,
                                                 bf16* __restrict__ perm) {
    __shared__ short lds[8192];                 // A: [0,4096) shorts, B: [4096,8192)

    const int tid  = threadIdx.x;
    const int wave = tid >> 6, lane = tid & 63;

    // XCD-aware decode: X=s&7 (XCD), jj=s>>3, G=X*56+jj/6 (n,b group), mt=jj%6.
    const int s  = blockIdx.x;
    const int X  = s & 7, jj = s >> 3;
    const int G  = X * 56 + jj / 6;             // (n,b) group in [0,448)
    const int mt = jj % 6;
    const int nt = G % 7;
    const int b  = G / 7;

    const int m0   = mt * 128;
    const int n0   = nt * 128;
    const int mw   = wave & 1, nw = wave >> 1;  // 2x2 wave grid of 64x64 tiles
    const int lrow = lane & 15, lkc = lane >> 4;  // fragment row / k-chunk

    f32x4 acc[4][4] = {};
    const bf16* xb = xT + (size_t)b * (HWH * 256);

    for (int k0 = 0; k0 < 256; k0 += 32) {
#pragma unroll
        for (int i = 0; i < 2; ++i) {
            const int jb = 2 * wave + i;        // fragment-block (16 rows)
            const bf16* ga = wbf + (size_t)(m0 + 16 * jb + lrow) * 256 + k0 + lkc * 8;
            load_lds16(ga, &lds[jb * 512]);
            int n = n0 + 16 * jb + lrow;
            if (n > HWH - 1) n = HWH - 1;       // clamp: OOB cols never stored
            const bf16* gb = xb + (size_t)n * 256 + k0 + lkc * 8;
            load_lds16(gb, &lds[4096 + jb * 512]);
        }
        __syncthreads();

        frag8 af[4], bf_[4];
#pragma unroll
        for (int i = 0; i < 4; ++i)
            af[i] = *reinterpret_cast<const frag8*>(&lds[(4 * mw + i) * 512 + lane * 8]);
#pragma unroll
        for (int j2 = 0; j2 < 4; ++j2)
            bf_[j2] = *reinterpret_cast<const frag8*>(&lds[4096 + (4 * nw + j2) * 512 + lane * 8]);
#pragma unroll
        for (int i = 0; i < 4; ++i)
#pragma unroll
            for (int j2 = 0; j2 < 4; ++j2)
                acc[i][j2] = __builtin_amdgcn_mfma_f32_16x16x32_bf16(
                    af[i], bf_[j2], acc[i][j2], 0, 0, 0);
        __syncthreads();
    }

    // Epilogue: C/D layout col=lane&15 (n), row=(lane>>4)*4+reg (m)
    // Store into padded plane position (y+1)*30 + (x+1) = col + 2*(col/28) + 31
#pragma unroll
    for (int i = 0; i < 4; ++i) {
        const int rowb = m0 + mw * 64 + i * 16 + lkc * 4;
        bf16* base[4]; float bias4[4];
#pragma unroll
        for (int r = 0; r < 4; ++r) {
            const int m = rowb + r;
            const int sec = m >> 8, ch = m & 255;
            base[r] = perm + ((size_t)b * 64 + (ch & 63)) * PBLK
                           + (size_t)(sec * 4 + (ch >> 6)) * PPLANE;
            bias4[r] = biascat[m];
        }
#pragma unroll
        for (int j2 = 0; j2 < 4; ++j2) {
            const int col = n0 + nw * 64 + j2 * 16 + lrow;
            if (col < HWH) {
                const int pos = col + 2 * (col / 28) + 31;
#pragma unroll
                for (int r = 0; r < 4; ++r)
                    base[r][pos] = __float2bfloat16(acc[i][j2][r] + bias4[r]);
            }
        }
    }
}

// ---------------------------------------------------------------------------
// attmean: interior 12x12 window means of v, prescaled by rate1/144.
// attm[b][c][25] f32. One wave per channel; lanes 0..27 own columns.
// v channel c lives at perm[b][c&63][8 + c/64] (bias already included).
// KEEP THIS KERNEL: perm is L3-resident right after gemm writes it, so this
// read is nearly free. The algebraic replacement (x-window means + W3 dot,
// R12-R14) was exact but NET SLOWER (+17 us); folding the dot into out_fused
// clamped it to 40 VGPR -> phase-C spill (104 us).
// ---------------------------------------------------------------------------
__global__ __launch_bounds__(256) void attmean(const bf16* __restrict__ perm,
                                               const float* __restrict__ rate1,
                                               float* __restrict__ attm) {
    const int b = blockIdx.y, cg = blockIdx.x;            // cg in [0,64)
    const int wave = threadIdx.x >> 6, lane = threadIdx.x & 63;
    const int c = cg * 4 + wave;                          // channel 0..255
    const bf16* vp = perm + ((size_t)(b * 64 + (c & 63)) * 12 + 8 + (c >> 6)) * (size_t)PPLANE;

    float cs[5] = {0.f, 0.f, 0.f, 0.f, 0.f};              // per-wi column sums
    if (lane < 28) {
#pragma unroll
        for (int y = 0; y < 28; ++y) {
            float v = __bfloat162float(vp[(y + 1) * PPITCH + lane + 1]);
#pragma unroll
            for (int wi = 0; wi < 5; ++wi)
                if (y >= 4 * wi && y <= 4 * wi + 11) cs[wi] += v;
        }
    }
    const float r1s = rate1[0] * (1.0f / 144.0f);
#pragma unroll
    for (int wi = 0; wi < 5; ++wi) {
        float p = cs[wi];
#pragma unroll
        for (int d = 1; d < 32; d <<= 1) {                // inclusive prefix over lanes
            float t = __shfl_up(p, d);
            if (lane >= d) p += t;
        }
        float hi = __shfl(p, 4 * lane + 11);              // valid for lane<5
        float lo = __shfl(p, 4 * lane - 1);
        if (lane < 5) {
            float w = hi - (lane ? lo : 0.f);
            attm[((size_t)b * 256 + c) * 25 + wi * 5 + lane] = w * r1s;
        }
    }
}

// ---------------------------------------------------------------------------
// out_fused5 (proven <68 us): out = attm + rate2 * conv.
// Phase A: uint4 plane copy (21.6 KB) + weights + attm load (precomputed).
// Phase A2: zero halo borders. Phase C: 3x3 conv, 196 thr x 4 oc x 4 px,
// pitch 30 (bank stride 15). LDS ~24.3 KB -> 6 blocks/CU.
// DO NOT add code to this kernel: R12 folded the attbs dot into phase A and
// the compiler clamped VGPR to 40 -> phase-C spills -> 104 us. Keep
// #pragma unroll 1 on the channel loop (R2: full unroll -> 256 VGPR spill).
// No launch-bounds min-waves (R1: (256,6) -> 40 VGPR catastrophe).
// ---------------------------------------------------------------------------
__global__ __launch_bounds__(256) void out_fused5(
    const bf16* __restrict__ perm, const float* __restrict__ W2,
    const float* __restrict__ attm, const float* __restrict__ rate2,
    float* __restrict__ out) {
    __shared__ __align__(16) short planes[12 * PPLANE];   // 21600 B, linear
    __shared__ float w2s[4][12][12];                      // [oc][c][k], k 9->12
    __shared__ float attbs[4][25];

    const int g = blockIdx.x, b = blockIdx.y, tid = threadIdx.x;

    // ---- phase A: linear LDS fill ----
    const uint4* src = (const uint4*)(perm + (size_t)(b * 64 + g) * PBLK);
#pragma unroll
    for (int it = 0; it < 6; ++it) {
        int e = tid + it * 256;                 // 1350 x 16B chunks
        if (e < 1350) ((uint4*)planes)[e] = src[e];
    }
    for (int e = tid; e < 576; e += 256) {
        int oc = e / 144, rem = e % 144, cc = rem / 12, k = rem % 12;
        w2s[oc][cc][k] = (k < 9) ? W2[(4 * g + oc) * 108 + cc * 9 + k] : 0.f;
    }
    if (tid < 100)
        attbs[tid / 25][tid % 25] =
            attm[((size_t)b * 256 + 4 * g + tid / 25) * 25 + tid % 25];
    __syncthreads();

    // ---- phase A2: zero halo borders (global borders hold garbage) ----
    for (int e = tid; e < 1392; e += 256) {
        int c12 = e / 116, u = e % 116, idx;
        if (u < 30)      idx = u;                         // top row
        else if (u < 60) idx = 870 + (u - 30);            // bottom row
        else { int v = u - 60; idx = ((v >> 1) + 1) * PPITCH + (v & 1) * 29; }
        planes[c12 * PPLANE + idx] = 0;
    }
    __syncthreads();

    // ---- phase C: conv. Lanes consecutive in y; bank stride 15 (odd). ----
    float acc[4][4] = {};   // [oc][px]
    const int y = tid % 28, xs = tid / 28, x0 = xs * 4;
    if (tid < 196) {
#pragma unroll 1   // CRITICAL: full unroll makes the scheduler hoist all 12
                   // channels' plane loads (~216 live floats) -> 256 VGPR + spill
        for (int c = 0; c < 12; ++c) {
            float rr[3][6];
#pragma unroll
            for (int dy = 0; dy < 3; ++dy) {
                const uint* row = (const uint*)&planes[c * PPLANE + (y + dy) * PPITCH + x0];
#pragma unroll
                for (int jp = 0; jp < 3; ++jp) {
                    uint w = row[jp];
                    float2 f = __bfloat1622float2(*(const __hip_bfloat162*)&w);
                    rr[dy][2 * jp]     = f.x;
                    rr[dy][2 * jp + 1] = f.y;
                }
            }
#pragma unroll
            for (int oc = 0; oc < 4; ++oc) {
                const float4* wr = reinterpret_cast<const float4*>(&w2s[oc][c][0]);
                float4 wa = wr[0], wb = wr[1], wc = wr[2];
                const float wk[9] = {wa.x, wa.y, wa.z, wa.w, wb.x, wb.y, wb.z, wb.w, wc.x};
#pragma unroll
                for (int ky = 0; ky < 3; ++ky)
#pragma unroll
                    for (int kx = 0; kx < 3; ++kx) {
                        float wv = wk[ky * 3 + kx];
#pragma unroll
                        for (int px = 0; px < 4; ++px)
                            acc[oc][px] += wv * rr[ky][px + kx];
                    }
            }
        }

        // ---- phase D: combine + store ----
        const float r2 = rate2[0];
        const int wi = (y >> 2) - 1, wj = xs - 1;
        const bool inter = (wi >= 0) & (wi < 5) & (wj >= 0) & (wj < 5);
#pragma unroll
        for (int oc = 0; oc < 4; ++oc) {
            float av = inter ? attbs[oc][wi * 5 + wj] : 0.f;
            float4 o;
            o.x = av + r2 * acc[oc][0];
            o.y = av + r2 * acc[oc][1];
            o.z = av + r2 * acc[oc][2];
            o.w = av + r2 * acc[oc][3];
            *reinterpret_cast<float4*>(
                &out[((size_t)(b * 256 + 4 * g + oc)) * HWH + y * 28 + x0]) = o;
        }
    }
}

// ---------------------------------------------------------------------------
extern "C" void kernel_launch(void* const* d_in, const int* in_sizes, int n_in,
                              void* d_out, int out_size, void* d_ws, size_t ws_size,
                              hipStream_t stream) {
    const float* x     = (const float*)d_in[0];
    const float* w1    = (const float*)d_in[1];
    const float* b1    = (const float*)d_in[2];
    const float* w2    = (const float*)d_in[3];
    const float* b2    = (const float*)d_in[4];
    const float* w3    = (const float*)d_in[5];
    const float* b3    = (const float*)d_in[6];
    const float* fc_w  = (const float*)d_in[7];
    const float* dep_w = (const float*)d_in[8];
    // d_in[9]/d_in[10] = rel_height/rel_width: provably dead (mask collapse)
    const float* rate1 = (const float*)d_in[11];
    const float* rate2 = (const float*)d_in[12];
    float* out = (float*)d_out;

    // workspace layout (bytes):
    //   perm    [0, 88473600)          64*64*12*900*2 (PADDED planes)
    //   xT      [88473600, 114163712)  64*784*256*2
    //   attm    = xT base (reused AFTER gemm consumes xT; stream-ordered)
    //   wbf     [114163712, 114556928) 768*256*2
    //   W2      [114556928, 114667520) 256*108*4
    //   biascat [114667520, 114670592) 768*4
    char* wsb = (char*)d_ws;
    bf16*  perm    = (bf16*)wsb;
    bf16*  xT      = (bf16*)(wsb + 88473600);
    float* attm    = (float*)(wsb + 88473600);           // alias of xT
    bf16*  wbf     = (bf16*)(wsb + 114163712);
    float* W2      = (float*)(wsb + 114556928);
    float* biascat = (float*)(wsb + 114667520);

    prep      <<<dim3(4204),       dim3(256), 0, stream>>>(x, w1, w2, w3, b1, b2, b3,
                                                           fc_w, dep_w, xT, wbf, W2, biascat);
    gemm_mfma <<<dim3(2688),       dim3(256), 0, stream>>>(wbf, biascat, xT, perm);
    attmean   <<<dim3(64, 64),     dim3(256), 0, stream>>>(perm, rate1, attm);
    out_fused5<<<dim3(64, 64),     dim3(256), 0, stream>>>(perm, W2, attm, rate2, out);
}